// Round 13
// baseline (385.820 us; speedup 1.0000x reference)
//
#include <hip/hip_runtime.h>
#include <hip/hip_bf16.h>

#define NE 8
#define TOK 16384
#define ND 512
#define NF 2048
#define HP 4608   // padded compact rows per expert in h (cnt ~4096, +9 sigma)
#define MT 36     // HP/128 t-tiles

typedef __attribute__((ext_vector_type(8))) short bf16x8;
typedef __attribute__((ext_vector_type(4))) float f32x4;
typedef unsigned short u16;
typedef unsigned long long u64;

#define WAITV(n) asm volatile("s_waitcnt vmcnt(" #n ")" ::: "memory")

__device__ __forceinline__ u16 f2bf(float f) {
  union { float f; unsigned u; } c; c.f = f;
  unsigned u = c.u;
  return (u16)((u + 0x7FFFu + ((u >> 16) & 1u)) >> 16);
}

// gelu(x) = x * (1 - 1/(exp2(K1*x + K2*x^3) + 1)),  K1 = sqrt(2/pi)*2*log2e
__device__ __forceinline__ float gelu_fast(float x) {
  float x2 = x * x;
  float zp = x * __builtin_fmaf(0.10294325f, x2, 2.3022084f);
  float u = __builtin_amdgcn_exp2f(zp);
  float r = __builtin_amdgcn_rcpf(u + 1.0f);   // u=inf -> r=0 -> y=x
  return x * (1.0f - r);
}

__device__ __forceinline__ void gl_lds16(const void* g, void* l) {
  __builtin_amdgcn_global_load_lds(
      (const __attribute__((address_space(1))) unsigned int*)g,
      (__attribute__((address_space(3))) unsigned int*)l, 16, 0, 0);
}

__device__ __forceinline__ int swzr(int row) { return ((row >> 1) & 3) << 4; }

// Transpose one [R][C] f32 plane per expert -> [C][R] bf16. (verified r10/r11)
__global__ void transpose_bf16(const float* __restrict__ in, u16* __restrict__ out,
                               int R, int C) {
  __shared__ float tile[32][33];
  int e = blockIdx.z;
  const float* ip = in + (size_t)e * R * C;
  u16* op = out + (size_t)e * R * C;
  int c0 = blockIdx.x * 32, r0 = blockIdx.y * 32;
  int tx = threadIdx.x & 31, ty = threadIdx.x >> 5;
  for (int i = 0; i < 32; i += 8)
    tile[ty + i][tx] = ip[(size_t)(r0 + ty + i) * C + (c0 + tx)];
  __syncthreads();
  for (int i = 0; i < 32; i += 8)
    op[(size_t)(c0 + ty + i) * R + (r0 + tx)] = f2bf(tile[tx][ty + i]);
}

__global__ void x_to_bf16(const float* __restrict__ x, u16* __restrict__ xbf) {
  int i = blockIdx.x * 256 + threadIdx.x;
  float4 v = ((const float4*)x)[i];
  union { u16 s[4]; u64 ll; } o;
  o.s[0] = f2bf(v.x); o.s[1] = f2bf(v.y); o.s[2] = f2bf(v.z); o.s[3] = f2bf(v.w);
  ((u64*)xbf)[i] = o.ll;
}

__global__ void zero_unmasked(const int* __restrict__ mask, float4* __restrict__ out4) {
  int row = blockIdx.x * 2 + (threadIdx.x >> 7);
  if (mask[row]) return;  // masked rows fully written by gemm2
  out4[(size_t)row * 128 + (threadIdx.x & 127)] = float4{0.f, 0.f, 0.f, 0.f};
}

__global__ void compact_mask(const int* __restrict__ mask, int* __restrict__ idx,
                             int* __restrict__ counts) {
  int e = blockIdx.x;
  __shared__ int wsum[4];
  __shared__ int base;
  if (threadIdx.x == 0) base = 0;
  const int* m = mask + (size_t)e * TOK;
  int lane = threadIdx.x & 63, w = threadIdx.x >> 6;
  for (int c0 = 0; c0 < TOK; c0 += 256) {
    __syncthreads();
    int i = c0 + threadIdx.x;
    int mi = (m[i] != 0);
    unsigned long long b = __ballot(mi);
    if (lane == 0) wsum[w] = __popcll(b);
    __syncthreads();
    int off = base;
    for (int ww = 0; ww < w; ww++) off += wsum[ww];
    off += __popcll(b & ((1ull << lane) - 1ull));
    if (mi) idx[(size_t)e * TOK + off] = i;
    __syncthreads();
    if (threadIdx.x == 0) base += wsum[0] + wsum[1] + wsum[2] + wsum[3];
  }
  __syncthreads();
  if (threadIdx.x == 0) counts[e] = base;
}

// GEMM1 (swapped operands): h^T-tile = W1-rows(M=f) x X-cols(N=t). 128x128, BK=32,
// 16 steps. T4 counted-vmcnt: 3 rotating buffers, stage 2 ahead, WAITV(4) per step
// (never drain mid-loop), raw s_barrier. 48 KB LDS -> 3 blocks/CU.
__launch_bounds__(256, 3)
__global__ void gemm1(const u16* __restrict__ xbf, const u16* __restrict__ W1t,
                      const float* __restrict__ b1f, const int* __restrict__ idx,
                      const int* __restrict__ counts, u16* __restrict__ h) {
  const int BPE = (NF / 128) * MT;   // 576
  int bid = blockIdx.x;
  int e = bid / BPE, r = bid % BPE;
  int f0 = (r / MT) * 128, t0 = (r % MT) * 128;
  int cnt = counts[e];
  if (t0 >= cnt) return;

  __shared__ __align__(16) u16 As[3][4096];  // [slot][128 f][32 d]
  __shared__ __align__(16) u16 Bs[3][4096];  // [slot][128 t][32 d]

  int tid = threadIdx.x, lane = tid & 63, w = tid >> 6;
  int wm = w & 1, wn = w >> 1;
  int l15 = lane & 15, l4 = lane >> 4;
  const int* idxe = idx + (size_t)e * TOK;

  int srow = lane >> 2, scolb = (lane & 3) << 4;
  int ar0 = w * 16 + srow, ar1 = 64 + w * 16 + srow;
  int cm1 = cnt - 1;
  int tk0 = idxe[t0 + ar0 <= cm1 ? t0 + ar0 : cm1];
  int tk1 = idxe[t0 + ar1 <= cm1 ? t0 + ar1 : cm1];
  const char* xb = (const char*)xbf;
  const char* w1 = (const char*)W1t;
  size_t asrc0 = ((size_t)e * NF + f0 + ar0) * 1024 + (scolb ^ swzr(ar0));
  size_t asrc1 = ((size_t)e * NF + f0 + ar1) * 1024 + (scolb ^ swzr(ar1));
  size_t bsrc0 = (size_t)tk0 * 1024 + (scolb ^ swzr(ar0));
  size_t bsrc1 = (size_t)tk1 * 1024 + (scolb ^ swzr(ar1));

  int aoff[4], boff[4];
  #pragma unroll
  for (int i = 0; i < 4; i++) {
    int rowa = wm * 64 + i * 16 + l15;
    aoff[i] = rowa * 64 + ((l4 * 16) ^ swzr(rowa));
    int rowb = wn * 64 + i * 16 + l15;
    boff[i] = rowb * 64 + ((l4 * 16) ^ swzr(rowb));
  }

  auto STAGE = [&](int kb, int s) {   // 4 loads/wave
    char* ad = (char*)As + s * 8192 + w * 1024 + lane * 16;
    char* bd = (char*)Bs + s * 8192 + w * 1024 + lane * 16;
    gl_lds16(w1 + asrc0 + kb * 64, ad);
    gl_lds16(w1 + asrc1 + kb * 64, ad + 4096);
    gl_lds16(xb + bsrc0 + kb * 64, bd);
    gl_lds16(xb + bsrc1 + kb * 64, bd + 4096);
  };

  f32x4 acc[4][4];
  #pragma unroll
  for (int i = 0; i < 4; i++)
    #pragma unroll
    for (int j = 0; j < 4; j++) acc[i][j] = (f32x4)(0.0f);

  STAGE(0, 0);
  STAGE(1, 1);

  #pragma unroll
  for (int kb = 0; kb < 16; ++kb) {
    int s = kb % 3;
    // outstanding before wait: stage(kb) [maybe] + stage(kb+1) [if exists].
    // WAITV(4) leaves only stage(kb+1) -> stage(kb) landed for this wave;
    // barrier makes that true for ALL waves. Last step: nothing beyond stage(15).
    if (kb < 15) WAITV(4);
    else         WAITV(0);
    __builtin_amdgcn_s_barrier();
    if (kb < 14) STAGE(kb + 2, (kb + 2) % 3);  // buf last read at step kb-1
    const char* ab = (const char*)As + s * 8192;
    const char* bb = (const char*)Bs + s * 8192;
    bf16x8 a[4], b[4];
    #pragma unroll
    for (int i = 0; i < 4; i++) a[i] = *(const bf16x8*)(ab + aoff[i]);
    #pragma unroll
    for (int j = 0; j < 4; j++) b[j] = *(const bf16x8*)(bb + boff[j]);
    #pragma unroll
    for (int i = 0; i < 4; i++)
      #pragma unroll
      for (int j = 0; j < 4; j++)
        acc[i][j] = __builtin_amdgcn_mfma_f32_16x16x32_bf16(a[i], b[j], acc[i][j], 0, 0, 0);
  }

  // epilogue: gelu(acc + b1) -> h[t][f], 4 consecutive f per thread -> u64 stores
  #pragma unroll
  for (int i = 0; i < 4; i++) {
    int fb = f0 + wm * 64 + i * 16 + l4 * 4;
    f32x4 bv = *(const f32x4*)(b1f + (size_t)e * NF + fb);
    #pragma unroll
    for (int j = 0; j < 4; j++) {
      int t = t0 + wn * 64 + j * 16 + l15;
      union { u16 s[4]; u64 ll; } pk;
      #pragma unroll
      for (int jj = 0; jj < 4; jj++)
        pk.s[jj] = f2bf(gelu_fast(acc[i][j][jj] + bv[jj]));
      *(u64*)(h + ((size_t)e * HP + t) * NF + fb) = pk.ll;
    }
  }
}

// GEMM2 (swapped operands): Y-tile = W2-rows(M=d) x h-cols(N=t). K=2048, 64 steps.
// Same T4 counted-vmcnt 3-buffer pipeline. Epilogue: f32x4 scatter (+b2).
__launch_bounds__(256, 3)
__global__ void gemm2(const u16* __restrict__ h, const u16* __restrict__ W2t,
                      const float* __restrict__ b2f, const int* __restrict__ idx,
                      const int* __restrict__ counts, float* __restrict__ out) {
  const int BPE = (ND / 128) * MT;   // 144
  int bid = blockIdx.x;
  int e = bid / BPE, r = bid % BPE;
  int d0 = (r / MT) * 128, t0 = (r % MT) * 128;
  int cnt = counts[e];
  if (t0 >= cnt) return;

  __shared__ __align__(16) u16 As[3][4096];  // [slot][128 d][32 f]
  __shared__ __align__(16) u16 Bs[3][4096];  // [slot][128 t][32 f]

  int tid = threadIdx.x, lane = tid & 63, w = tid >> 6;
  int wm = w & 1, wn = w >> 1;
  int l15 = lane & 15, l4 = lane >> 4;
  const int* idxe = idx + (size_t)e * TOK;

  int srow = lane >> 2, scolb = (lane & 3) << 4;
  int ar0 = w * 16 + srow, ar1 = 64 + w * 16 + srow;
  const char* hb = (const char*)h;
  const char* w2 = (const char*)W2t;
  size_t asrc0 = ((size_t)e * ND + d0 + ar0) * 4096 + (scolb ^ swzr(ar0));
  size_t asrc1 = ((size_t)e * ND + d0 + ar1) * 4096 + (scolb ^ swzr(ar1));
  size_t bsrc0 = ((size_t)e * HP + t0 + ar0) * 4096 + (scolb ^ swzr(ar0));
  size_t bsrc1 = ((size_t)e * HP + t0 + ar1) * 4096 + (scolb ^ swzr(ar1));

  int aoff[4], boff[4];
  #pragma unroll
  for (int i = 0; i < 4; i++) {
    int rowa = wm * 64 + i * 16 + l15;
    aoff[i] = rowa * 64 + ((l4 * 16) ^ swzr(rowa));
    int rowb = wn * 64 + i * 16 + l15;
    boff[i] = rowb * 64 + ((l4 * 16) ^ swzr(rowb));
  }

  auto STAGE = [&](int kb, int s) {   // 4 loads/wave
    char* ad = (char*)As + s * 8192 + w * 1024 + lane * 16;
    char* bd = (char*)Bs + s * 8192 + w * 1024 + lane * 16;
    gl_lds16(w2 + asrc0 + kb * 64, ad);
    gl_lds16(w2 + asrc1 + kb * 64, ad + 4096);
    gl_lds16(hb + bsrc0 + kb * 64, bd);
    gl_lds16(hb + bsrc1 + kb * 64, bd + 4096);
  };

  f32x4 acc[4][4];
  #pragma unroll
  for (int i = 0; i < 4; i++)
    #pragma unroll
    for (int j = 0; j < 4; j++) acc[i][j] = (f32x4)(0.0f);

  STAGE(0, 0);
  STAGE(1, 1);

  int s0 = 0, s1 = 1, s2 = 2;
  #pragma unroll 3
  for (int kb = 0; kb < 63; ++kb) {   // steps 0..62 (step 63 peeled)
    WAITV(4);                          // stage(kb) landed; stage(kb+1) in flight
    __builtin_amdgcn_s_barrier();
    if (kb < 62) STAGE(kb + 2, s2);    // buf last read at step kb-1
    const char* ab = (const char*)As + s0 * 8192;
    const char* bb = (const char*)Bs + s0 * 8192;
    bf16x8 a[4], b[4];
    #pragma unroll
    for (int i = 0; i < 4; i++) a[i] = *(const bf16x8*)(ab + aoff[i]);
    #pragma unroll
    for (int j = 0; j < 4; j++) b[j] = *(const bf16x8*)(bb + boff[j]);
    #pragma unroll
    for (int i = 0; i < 4; i++)
      #pragma unroll
      for (int j = 0; j < 4; j++)
        acc[i][j] = __builtin_amdgcn_mfma_f32_16x16x32_bf16(a[i], b[j], acc[i][j], 0, 0, 0);
    int tt = s0; s0 = s1; s1 = s2; s2 = tt;
  }
  {  // step 63
    WAITV(0);
    __builtin_amdgcn_s_barrier();
    const char* ab = (const char*)As + s0 * 8192;
    const char* bb = (const char*)Bs + s0 * 8192;
    bf16x8 a[4], b[4];
    #pragma unroll
    for (int i = 0; i < 4; i++) a[i] = *(const bf16x8*)(ab + aoff[i]);
    #pragma unroll
    for (int j = 0; j < 4; j++) b[j] = *(const bf16x8*)(bb + boff[j]);
    #pragma unroll
    for (int i = 0; i < 4; i++)
      #pragma unroll
      for (int j = 0; j < 4; j++)
        acc[i][j] = __builtin_amdgcn_mfma_f32_16x16x32_bf16(a[i], b[j], acc[i][j], 0, 0, 0);
  }

  // epilogue: +b2, f32x4 scatter per (i,j), 4 consecutive d per thread
  #pragma unroll
  for (int i = 0; i < 4; i++) {
    int db = d0 + wm * 64 + i * 16 + l4 * 4;
    f32x4 b2v = *(const f32x4*)(b2f + (size_t)e * ND + db);
    #pragma unroll
    for (int j = 0; j < 4; j++) {
      int t = t0 + wn * 64 + j * 16 + l15;
      if (t < cnt) {
        int tok = idxe[t];
        f32x4 v;
        #pragma unroll
        for (int jj = 0; jj < 4; jj++) v[jj] = acc[i][j][jj] + b2v[jj];
        *(f32x4*)(out + ((size_t)e * TOK + tok) * ND + db) = v;
      }
    }
  }
}

extern "C" void kernel_launch(void* const* d_in, const int* in_sizes, int n_in,
                              void* d_out, int out_size, void* d_ws, size_t ws_size,
                              hipStream_t stream) {
  const float* x  = (const float*)d_in[0];
  const float* W1 = (const float*)d_in[1];
  const float* b1 = (const float*)d_in[2];
  const float* W2 = (const float*)d_in[3];
  const float* b2 = (const float*)d_in[4];
  const int* mask = (const int*)d_in[5];

  char* ws = (char*)d_ws;
  int* counts = (int*)ws;                                   // 1 KiB
  int* idx    = (int*)(ws + 1024);                          // 512 KiB
  u16* W1t    = (u16*)(ws + 1024 + (size_t)NE * TOK * 4);   // 16 MiB  [E][f][d]
  u16* W2t    = W1t + (size_t)NE * NF * ND;                 // 16 MiB  [E][d][f]
  u16* xbf    = W2t + (size_t)NE * ND * NF;                 // 16 MiB
  u16* h      = xbf + (size_t)TOK * ND;                     // 151 MiB [E][HP][NF]

  zero_unmasked<<<dim3(NE * TOK / 2), dim3(256), 0, stream>>>(mask, (float4*)d_out);
  transpose_bf16<<<dim3(NF / 32, ND / 32, NE), dim3(256), 0, stream>>>(W1, W1t, ND, NF);
  transpose_bf16<<<dim3(ND / 32, NF / 32, NE), dim3(256), 0, stream>>>(W2, W2t, NF, ND);
  x_to_bf16<<<dim3(TOK * ND / 4 / 256), dim3(256), 0, stream>>>(x, xbf);
  compact_mask<<<dim3(NE), dim3(256), 0, stream>>>(mask, idx, counts);

  gemm1<<<dim3(NE * (NF / 128) * MT), dim3(256), 0, stream>>>(xbf, W1t, b1, idx, counts, h);
  gemm2<<<dim3(NE * (ND / 128) * MT), dim3(256), 0, stream>>>(h, W2t, b2, idx, counts,
                                                              (float*)d_out);
}

// Round 14
// 380.836 us; speedup vs baseline: 1.0131x; 1.0131x over previous
//
#include <hip/hip_runtime.h>
#include <hip/hip_bf16.h>

#define NE 8
#define TOK 16384
#define ND 512
#define NF 2048
#define HP 4608   // padded compact rows per expert (cnt ~4096, +9 sigma)

typedef __attribute__((ext_vector_type(8))) short bf16x8;
typedef __attribute__((ext_vector_type(4))) float f32x4;
typedef unsigned short u16;
typedef unsigned long long u64;

#define WAITV(n) asm volatile("s_waitcnt vmcnt(" #n ")" ::: "memory")
#define LGKM0()  asm volatile("s_waitcnt lgkmcnt(0)" ::: "memory")
#define SBAR()   __builtin_amdgcn_s_barrier()
#define PRIO(p)  __builtin_amdgcn_s_setprio(p)

__device__ __forceinline__ u16 f2bf(float f) {
  union { float f; unsigned u; } c; c.f = f;
  unsigned u = c.u;
  return (u16)((u + 0x7FFFu + ((u >> 16) & 1u)) >> 16);
}

// gelu(x) = x * (1 - 1/(exp2(K1*x + K2*x^3) + 1)),  K1 = sqrt(2/pi)*2*log2e
__device__ __forceinline__ float gelu_fast(float x) {
  float x2 = x * x;
  float zp = x * __builtin_fmaf(0.10294325f, x2, 2.3022084f);
  float u = __builtin_amdgcn_exp2f(zp);
  float r = __builtin_amdgcn_rcpf(u + 1.0f);   // u=inf -> r=0 -> y=x
  return x * (1.0f - r);
}

__device__ __forceinline__ void gl_lds16(const void* g, void* l) {
  __builtin_amdgcn_global_load_lds(
      (const __attribute__((address_space(1))) unsigned int*)g,
      (__attribute__((address_space(3))) unsigned int*)l, 16, 0, 0);
}

// Transpose one [R][C] f32 plane per expert -> [C][R] bf16. (verified r10-r12)
__global__ void transpose_bf16(const float* __restrict__ in, u16* __restrict__ out,
                               int R, int C) {
  __shared__ float tile[32][33];
  int e = blockIdx.z;
  const float* ip = in + (size_t)e * R * C;
  u16* op = out + (size_t)e * R * C;
  int c0 = blockIdx.x * 32, r0 = blockIdx.y * 32;
  int tx = threadIdx.x & 31, ty = threadIdx.x >> 5;
  for (int i = 0; i < 32; i += 8)
    tile[ty + i][tx] = ip[(size_t)(r0 + ty + i) * C + (c0 + tx)];
  __syncthreads();
  for (int i = 0; i < 32; i += 8)
    op[(size_t)(c0 + ty + i) * R + (r0 + tx)] = f2bf(tile[tx][ty + i]);
}

__global__ void x_to_bf16(const float* __restrict__ x, u16* __restrict__ xbf) {
  int i = blockIdx.x * 256 + threadIdx.x;
  float4 v = ((const float4*)x)[i];
  union { u16 s[4]; u64 ll; } o;
  o.s[0] = f2bf(v.x); o.s[1] = f2bf(v.y); o.s[2] = f2bf(v.z); o.s[3] = f2bf(v.w);
  ((u64*)xbf)[i] = o.ll;
}

__global__ void zero_unmasked(const int* __restrict__ mask, float4* __restrict__ out4) {
  int row = blockIdx.x * 2 + (threadIdx.x >> 7);
  if (mask[row]) return;  // masked rows fully written by gemm2
  out4[(size_t)row * 128 + (threadIdx.x & 127)] = float4{0.f, 0.f, 0.f, 0.f};
}

__global__ void compact_mask(const int* __restrict__ mask, int* __restrict__ idx,
                             int* __restrict__ counts) {
  int e = blockIdx.x;
  __shared__ int wsum[4];
  __shared__ int base;
  if (threadIdx.x == 0) base = 0;
  const int* m = mask + (size_t)e * TOK;
  int lane = threadIdx.x & 63, w = threadIdx.x >> 6;
  for (int c0 = 0; c0 < TOK; c0 += 256) {
    __syncthreads();
    int i = c0 + threadIdx.x;
    int mi = (m[i] != 0);
    unsigned long long b = __ballot(mi);
    if (lane == 0) wsum[w] = __popcll(b);
    __syncthreads();
    int off = base;
    for (int ww = 0; ww < w; ww++) off += wsum[ww];
    off += __popcll(b & ((1ull << lane) - 1ull));
    if (mi) idx[(size_t)e * TOK + off] = i;
    __syncthreads();
    if (threadIdx.x == 0) base += wsum[0] + wsum[1] + wsum[2] + wsum[3];
  }
  __syncthreads();
  if (threadIdx.x == 0) counts[e] = base;
}

// ---------------------------------------------------------------------------
// Phase-split GEMM core. Tile 128(M) x 256(N) x BK=64. 8 waves (2M x 4N),
// wave 64x64. 3 LDS bufs x 48KB. Per K-tile: 4 phases
//   {stage one 16KB unit of tile t+2 | ds_read next phase's frags | 8 MFMA}
// vmcnt(6) once per K-tile (ph3) -> tile t+1 fully landed before ph4 reads it.
// ---------------------------------------------------------------------------

// GEMM1: h[t][f] = gelu(x @ W1 + b1) per expert. A=W1t rows f (pitch 1024B),
// B=x rows t gathered via idx (pitch 1024B), K=512 -> nt=8 K-tiles.
__launch_bounds__(512, 2)
__global__ void gemm1(const u16* __restrict__ xbf, const u16* __restrict__ W1t,
                      const float* __restrict__ b1f, const int* __restrict__ idx,
                      const int* __restrict__ counts, u16* __restrict__ h) {
  int bid = blockIdx.x;
  int e = bid / 288, r = bid % 288;      // 16 f-tiles x 18 t-tiles
  int f0 = (r / 18) * 128, t0 = (r % 18) * 256;
  int cnt = counts[e];
  if (t0 >= cnt) return;

  __shared__ __align__(16) u16 lds[3 * 24576];   // 144 KB

  int tid = threadIdx.x, lane = tid & 63, w = tid >> 6;
  int wm = w & 1, wn = w >> 1;
  int l15 = lane & 15, l4 = lane >> 4;
  const int* idxe = idx + (size_t)e * TOK;
  int cm1 = cnt - 1;

  // stage-source precompute: unit = 128 rows x 128B; thread covers row srow(+8)
  int srow = w * 16 + (lane >> 3);
  int ssw = ((lane & 7) * 16) ^ ((srow & 7) << 4);   // (row&7) invariant под +8/+128
  const char* w1 = (const char*)W1t;
  const char* xb = (const char*)xbf;
  size_t aS = ((size_t)e * NF + f0 + srow) * 1024 + ssw;
  int tA0 = idxe[(t0 + srow)       <= cm1 ? (t0 + srow)       : cm1];
  int tA1 = idxe[(t0 + srow + 8)   <= cm1 ? (t0 + srow + 8)   : cm1];
  int tB0 = idxe[(t0 + srow + 128) <= cm1 ? (t0 + srow + 128) : cm1];
  int tB1 = idxe[(t0 + srow + 136) <= cm1 ? (t0 + srow + 136) : cm1];
  size_t xS0 = (size_t)tA0 * 1024 + ssw, xS1 = (size_t)tA1 * 1024 + ssw;
  size_t xS2 = (size_t)tB0 * 1024 + ssw, xS3 = (size_t)tB1 * 1024 + ssw;

  // ds-read frag offsets (byte, buf-relative). A rows 128 (16KB), B rows 256 (32KB @+16KB)
  int aoff[4][2], boff[4][2];
  #pragma unroll
  for (int i = 0; i < 4; i++) {
    int ra = wm * 64 + i * 16 + l15;
    int rb = wn * 64 + i * 16 + l15;
    #pragma unroll
    for (int ks = 0; ks < 2; ks++) {
      aoff[i][ks] = ra * 128 + ((ks * 64 + l4 * 16) ^ ((ra & 7) << 4));
      boff[i][ks] = 16384 + rb * 128 + ((ks * 64 + l4 * 16) ^ ((rb & 7) << 4));
    }
  }

  auto SA = [&](int kt, char* bp) {          // A unit: 2 loads/thread
    char* d = bp + w * 2048;
    gl_lds16(w1 + aS + kt * 128, d);
    gl_lds16(w1 + aS + 8192 + kt * 128, d + 1024);
  };
  auto SB0 = [&](int kt, char* bp) {         // B rows 0-127
    char* d = bp + 16384 + w * 2048;
    gl_lds16(xb + xS0 + kt * 128, d);
    gl_lds16(xb + xS1 + kt * 128, d + 1024);
  };
  auto SB1 = [&](int kt, char* bp) {         // B rows 128-255
    char* d = bp + 32768 + w * 2048;
    gl_lds16(xb + xS2 + kt * 128, d);
    gl_lds16(xb + xS3 + kt * 128, d + 1024);
  };

  char* bc = (char*)lds;            // tile t
  char* bn = (char*)lds + 49152;    // tile t+1
  char* bs = (char*)lds + 98304;    // tile t+2

  SA(0, bc); SB0(0, bc); SB1(0, bc);
  SA(1, bn); SB0(1, bn); SB1(1, bn);
  WAITV(6);          // tile 0 landed (tile 1's 6 loads in flight)
  SBAR();

  f32x4 acc[4][4];
  #pragma unroll
  for (int i = 0; i < 4; i++)
    #pragma unroll
    for (int j = 0; j < 4; j++) acc[i][j] = (f32x4)(0.0f);

  bf16x8 A0[4], A1[4], Ba[2], Bb[2];
  #pragma unroll
  for (int i = 0; i < 4; i++) A0[i] = *(const bf16x8*)(bc + aoff[i][0]);
  Ba[0] = *(const bf16x8*)(bc + boff[0][0]);
  Ba[1] = *(const bf16x8*)(bc + boff[1][0]);

  const int nt = 8;
  for (int t = 0; t < nt; ++t) {
    bool stg = (t + 2 < nt);
    // ---- ph1: MFMA A0 x Ba (j=0,1, k0); read Bb(k0); stage A(t+2) ----
    if (stg) SA(t + 2, bs);
    Bb[0] = *(const bf16x8*)(bc + boff[2][0]);
    Bb[1] = *(const bf16x8*)(bc + boff[3][0]);
    PRIO(1);
    #pragma unroll
    for (int i = 0; i < 4; i++) {
      acc[i][0] = __builtin_amdgcn_mfma_f32_16x16x32_bf16(A0[i], Ba[0], acc[i][0], 0, 0, 0);
      acc[i][1] = __builtin_amdgcn_mfma_f32_16x16x32_bf16(A0[i], Ba[1], acc[i][1], 0, 0, 0);
    }
    PRIO(0);
    LGKM0(); SBAR();
    // ---- ph2: MFMA A0 x Bb (j=2,3, k0); read A1(k1), Ba(k1); stage B0(t+2) ----
    if (stg) SB0(t + 2, bs);
    #pragma unroll
    for (int i = 0; i < 4; i++) A1[i] = *(const bf16x8*)(bc + aoff[i][1]);
    Ba[0] = *(const bf16x8*)(bc + boff[0][1]);
    Ba[1] = *(const bf16x8*)(bc + boff[1][1]);
    PRIO(1);
    #pragma unroll
    for (int i = 0; i < 4; i++) {
      acc[i][2] = __builtin_amdgcn_mfma_f32_16x16x32_bf16(A0[i], Bb[0], acc[i][2], 0, 0, 0);
      acc[i][3] = __builtin_amdgcn_mfma_f32_16x16x32_bf16(A0[i], Bb[1], acc[i][3], 0, 0, 0);
    }
    PRIO(0);
    LGKM0(); SBAR();
    // ---- ph3: MFMA A1 x Ba (j=0,1, k1); read Bb(k1); stage B1(t+2); vmcnt ----
    if (stg) SB1(t + 2, bs);
    Bb[0] = *(const bf16x8*)(bc + boff[2][1]);
    Bb[1] = *(const bf16x8*)(bc + boff[3][1]);
    PRIO(1);
    #pragma unroll
    for (int i = 0; i < 4; i++) {
      acc[i][0] = __builtin_amdgcn_mfma_f32_16x16x32_bf16(A1[i], Ba[0], acc[i][0], 0, 0, 0);
      acc[i][1] = __builtin_amdgcn_mfma_f32_16x16x32_bf16(A1[i], Ba[1], acc[i][1], 0, 0, 0);
    }
    PRIO(0);
    if (stg) WAITV(6);   // drain tile t+1's 6 loads; keep t+2's in flight
    else     WAITV(0);
    LGKM0(); SBAR();
    // ---- ph4: MFMA A1 x Bb (j=2,3, k1); read next tile's A0(k0), Ba(k0) ----
    if (t + 1 < nt) {
      #pragma unroll
      for (int i = 0; i < 4; i++) A0[i] = *(const bf16x8*)(bn + aoff[i][0]);
      Ba[0] = *(const bf16x8*)(bn + boff[0][0]);
      Ba[1] = *(const bf16x8*)(bn + boff[1][0]);
    }
    PRIO(1);
    #pragma unroll
    for (int i = 0; i < 4; i++) {
      acc[i][2] = __builtin_amdgcn_mfma_f32_16x16x32_bf16(A1[i], Bb[0], acc[i][2], 0, 0, 0);
      acc[i][3] = __builtin_amdgcn_mfma_f32_16x16x32_bf16(A1[i], Bb[1], acc[i][3], 0, 0, 0);
    }
    PRIO(0);
    LGKM0(); SBAR();
    char* tp = bc; bc = bn; bn = bs; bs = tp;
  }

  // epilogue: gelu(acc + b1) -> h[t][f], packed u64 (4 consecutive f)
  #pragma unroll
  for (int i = 0; i < 4; i++) {
    int fb = f0 + wm * 64 + i * 16 + l4 * 4;
    f32x4 bv = *(const f32x4*)(b1f + (size_t)e * NF + fb);
    #pragma unroll
    for (int j = 0; j < 4; j++) {
      int t = t0 + wn * 64 + j * 16 + l15;
      union { u16 s[4]; u64 ll; } pk;
      #pragma unroll
      for (int jj = 0; jj < 4; jj++)
        pk.s[jj] = f2bf(gelu_fast(acc[i][j][jj] + bv[jj]));
      *(u64*)(h + ((size_t)e * HP + t) * NF + fb) = pk.ll;
    }
  }
}

// GEMM2: Y = h @ W2 + b2, scatter via idx. A=W2t rows d (pitch 4096B),
// B=h rows t contiguous (pitch 4096B), K=2048 -> nt=32 K-tiles.
__launch_bounds__(512, 2)
__global__ void gemm2(const u16* __restrict__ h, const u16* __restrict__ W2t,
                      const float* __restrict__ b2f, const int* __restrict__ idx,
                      const int* __restrict__ counts, float* __restrict__ out) {
  int bid = blockIdx.x;
  int e = bid / 72, r = bid % 72;        // 4 d-tiles x 18 t-tiles
  int d0 = (r / 18) * 128, t0 = (r % 18) * 256;
  int cnt = counts[e];
  if (t0 >= cnt) return;

  __shared__ __align__(16) u16 lds[3 * 24576];   // 144 KB

  int tid = threadIdx.x, lane = tid & 63, w = tid >> 6;
  int wm = w & 1, wn = w >> 1;
  int l15 = lane & 15, l4 = lane >> 4;
  const int* idxe = idx + (size_t)e * TOK;

  int srow = w * 16 + (lane >> 3);
  int ssw = ((lane & 7) * 16) ^ ((srow & 7) << 4);
  const char* w2 = (const char*)W2t;
  const char* hb = (const char*)h;
  size_t aS = ((size_t)e * ND + d0 + srow) * 4096 + ssw;
  size_t bS = ((size_t)e * HP + t0 + srow) * 4096 + ssw;

  int aoff[4][2], boff[4][2];
  #pragma unroll
  for (int i = 0; i < 4; i++) {
    int ra = wm * 64 + i * 16 + l15;
    int rb = wn * 64 + i * 16 + l15;
    #pragma unroll
    for (int ks = 0; ks < 2; ks++) {
      aoff[i][ks] = ra * 128 + ((ks * 64 + l4 * 16) ^ ((ra & 7) << 4));
      boff[i][ks] = 16384 + rb * 128 + ((ks * 64 + l4 * 16) ^ ((rb & 7) << 4));
    }
  }

  auto SA = [&](int kt, char* bp) {
    char* d = bp + w * 2048;
    gl_lds16(w2 + aS + kt * 128, d);
    gl_lds16(w2 + aS + 8 * 4096 + kt * 128, d + 1024);
  };
  auto SB0 = [&](int kt, char* bp) {
    char* d = bp + 16384 + w * 2048;
    gl_lds16(hb + bS + kt * 128, d);
    gl_lds16(hb + bS + 8 * 4096 + kt * 128, d + 1024);
  };
  auto SB1 = [&](int kt, char* bp) {
    char* d = bp + 32768 + w * 2048;
    gl_lds16(hb + bS + 128 * 4096 + kt * 128, d);
    gl_lds16(hb + bS + 136 * 4096 + kt * 128, d + 1024);
  };

  char* bc = (char*)lds;
  char* bn = (char*)lds + 49152;
  char* bs = (char*)lds + 98304;

  SA(0, bc); SB0(0, bc); SB1(0, bc);
  SA(1, bn); SB0(1, bn); SB1(1, bn);
  WAITV(6);
  SBAR();

  f32x4 acc[4][4];
  #pragma unroll
  for (int i = 0; i < 4; i++)
    #pragma unroll
    for (int j = 0; j < 4; j++) acc[i][j] = (f32x4)(0.0f);

  bf16x8 A0[4], A1[4], Ba[2], Bb[2];
  #pragma unroll
  for (int i = 0; i < 4; i++) A0[i] = *(const bf16x8*)(bc + aoff[i][0]);
  Ba[0] = *(const bf16x8*)(bc + boff[0][0]);
  Ba[1] = *(const bf16x8*)(bc + boff[1][0]);

  const int nt = 32;
  for (int t = 0; t < nt; ++t) {
    bool stg = (t + 2 < nt);
    if (stg) SA(t + 2, bs);
    Bb[0] = *(const bf16x8*)(bc + boff[2][0]);
    Bb[1] = *(const bf16x8*)(bc + boff[3][0]);
    PRIO(1);
    #pragma unroll
    for (int i = 0; i < 4; i++) {
      acc[i][0] = __builtin_amdgcn_mfma_f32_16x16x32_bf16(A0[i], Ba[0], acc[i][0], 0, 0, 0);
      acc[i][1] = __builtin_amdgcn_mfma_f32_16x16x32_bf16(A0[i], Ba[1], acc[i][1], 0, 0, 0);
    }
    PRIO(0);
    LGKM0(); SBAR();
    if (stg) SB0(t + 2, bs);
    #pragma unroll
    for (int i = 0; i < 4; i++) A1[i] = *(const bf16x8*)(bc + aoff[i][1]);
    Ba[0] = *(const bf16x8*)(bc + boff[0][1]);
    Ba[1] = *(const bf16x8*)(bc + boff[1][1]);
    PRIO(1);
    #pragma unroll
    for (int i = 0; i < 4; i++) {
      acc[i][2] = __builtin_amdgcn_mfma_f32_16x16x32_bf16(A0[i], Bb[0], acc[i][2], 0, 0, 0);
      acc[i][3] = __builtin_amdgcn_mfma_f32_16x16x32_bf16(A0[i], Bb[1], acc[i][3], 0, 0, 0);
    }
    PRIO(0);
    LGKM0(); SBAR();
    if (stg) SB1(t + 2, bs);
    Bb[0] = *(const bf16x8*)(bc + boff[2][1]);
    Bb[1] = *(const bf16x8*)(bc + boff[3][1]);
    PRIO(1);
    #pragma unroll
    for (int i = 0; i < 4; i++) {
      acc[i][0] = __builtin_amdgcn_mfma_f32_16x16x32_bf16(A1[i], Ba[0], acc[i][0], 0, 0, 0);
      acc[i][1] = __builtin_amdgcn_mfma_f32_16x16x32_bf16(A1[i], Ba[1], acc[i][1], 0, 0, 0);
    }
    PRIO(0);
    if (stg) WAITV(6);
    else     WAITV(0);
    LGKM0(); SBAR();
    if (t + 1 < nt) {
      #pragma unroll
      for (int i = 0; i < 4; i++) A0[i] = *(const bf16x8*)(bn + aoff[i][0]);
      Ba[0] = *(const bf16x8*)(bn + boff[0][0]);
      Ba[1] = *(const bf16x8*)(bn + boff[1][0]);
    }
    PRIO(1);
    #pragma unroll
    for (int i = 0; i < 4; i++) {
      acc[i][2] = __builtin_amdgcn_mfma_f32_16x16x32_bf16(A1[i], Bb[0], acc[i][2], 0, 0, 0);
      acc[i][3] = __builtin_amdgcn_mfma_f32_16x16x32_bf16(A1[i], Bb[1], acc[i][3], 0, 0, 0);
    }
    PRIO(0);
    LGKM0(); SBAR();
    char* tp = bc; bc = bn; bn = bs; bs = tp;
  }

  // epilogue: +b2, f32x4 scatter (4 consecutive d), guard t < cnt
  #pragma unroll
  for (int i = 0; i < 4; i++) {
    int db = d0 + wm * 64 + i * 16 + l4 * 4;
    f32x4 b2v = *(const f32x4*)(b2f + (size_t)e * ND + db);
    #pragma unroll
    for (int j = 0; j < 4; j++) {
      int t = t0 + wn * 64 + j * 16 + l15;
      if (t < cnt) {
        int tok = idxe[t];
        f32x4 v;
        #pragma unroll
        for (int jj = 0; jj < 4; jj++) v[jj] = acc[i][j][jj] + b2v[jj];
        *(f32x4*)(out + ((size_t)e * TOK + tok) * ND + db) = v;
      }
    }
  }
}

extern "C" void kernel_launch(void* const* d_in, const int* in_sizes, int n_in,
                              void* d_out, int out_size, void* d_ws, size_t ws_size,
                              hipStream_t stream) {
  const float* x  = (const float*)d_in[0];
  const float* W1 = (const float*)d_in[1];
  const float* b1 = (const float*)d_in[2];
  const float* W2 = (const float*)d_in[3];
  const float* b2 = (const float*)d_in[4];
  const int* mask = (const int*)d_in[5];

  char* ws = (char*)d_ws;
  int* counts = (int*)ws;                                   // 1 KiB
  int* idx    = (int*)(ws + 1024);                          // 512 KiB
  u16* W1t    = (u16*)(ws + 1024 + (size_t)NE * TOK * 4);   // 16 MiB  [E][f][d]
  u16* W2t    = W1t + (size_t)NE * NF * ND;                 // 16 MiB  [E][d][f]
  u16* xbf    = W2t + (size_t)NE * ND * NF;                 // 16 MiB
  u16* h      = xbf + (size_t)TOK * ND;                     // 151 MiB [E][HP][NF]

  zero_unmasked<<<dim3(NE * TOK / 2), dim3(256), 0, stream>>>(mask, (float4*)d_out);
  transpose_bf16<<<dim3(NF / 32, ND / 32, NE), dim3(256), 0, stream>>>(W1, W1t, ND, NF);
  transpose_bf16<<<dim3(ND / 32, NF / 32, NE), dim3(256), 0, stream>>>(W2, W2t, NF, ND);
  x_to_bf16<<<dim3(TOK * ND / 4 / 256), dim3(256), 0, stream>>>(x, xbf);
  compact_mask<<<dim3(NE), dim3(256), 0, stream>>>(mask, idx, counts);

  gemm1<<<dim3(NE * 16 * 18), dim3(512), 0, stream>>>(xbf, W1t, b1, idx, counts, h);
  gemm2<<<dim3(NE * 4 * 18), dim3(512), 0, stream>>>(h, W2t, b2, idx, counts,
                                                     (float*)d_out);
}

// Round 15
// 374.897 us; speedup vs baseline: 1.0291x; 1.0158x over previous
//
#include <hip/hip_runtime.h>
#include <hip/hip_bf16.h>

#define NE 8
#define TOK 16384
#define ND 512
#define NF 2048
#define HP 4608   // padded compact rows per expert (cnt ~4096, +9 sigma)
#define MT 36     // HP/128 t-tiles

typedef __attribute__((ext_vector_type(8))) short bf16x8;
typedef __attribute__((ext_vector_type(4))) float f32x4;
typedef unsigned short u16;
typedef unsigned long long u64;

__device__ __forceinline__ u16 f2bf(float f) {
  union { float f; unsigned u; } c; c.f = f;
  unsigned u = c.u;
  return (u16)((u + 0x7FFFu + ((u >> 16) & 1u)) >> 16);
}

// gelu(x) = x * (1 - 1/(exp2(K1*x + K2*x^3) + 1)),  K1 = sqrt(2/pi)*2*log2e
__device__ __forceinline__ float gelu_fast(float x) {
  float x2 = x * x;
  float zp = x * __builtin_fmaf(0.10294325f, x2, 2.3022084f);
  float u = __builtin_amdgcn_exp2f(zp);
  float r = __builtin_amdgcn_rcpf(u + 1.0f);   // u=inf -> r=0 -> y=x
  return x * (1.0f - r);
}

__device__ __forceinline__ void gl_lds16(const void* g, void* l) {
  __builtin_amdgcn_global_load_lds(
      (const __attribute__((address_space(1))) unsigned int*)g,
      (__attribute__((address_space(3))) unsigned int*)l, 16, 0, 0);
}

__device__ __forceinline__ int swzr(int row) { return ((row >> 1) & 3) << 4; }

// Transpose one [R][C] f32 plane per expert -> [C][R] bf16. (verified r10-r13)
__global__ void transpose_bf16(const float* __restrict__ in, u16* __restrict__ out,
                               int R, int C) {
  __shared__ float tile[32][33];
  int e = blockIdx.z;
  const float* ip = in + (size_t)e * R * C;
  u16* op = out + (size_t)e * R * C;
  int c0 = blockIdx.x * 32, r0 = blockIdx.y * 32;
  int tx = threadIdx.x & 31, ty = threadIdx.x >> 5;
  for (int i = 0; i < 32; i += 8)
    tile[ty + i][tx] = ip[(size_t)(r0 + ty + i) * C + (c0 + tx)];
  __syncthreads();
  for (int i = 0; i < 32; i += 8)
    op[(size_t)(c0 + ty + i) * R + (r0 + tx)] = f2bf(tile[tx][ty + i]);
}

__global__ void zero_unmasked(const int* __restrict__ mask, float4* __restrict__ out4) {
  int row = blockIdx.x * 2 + (threadIdx.x >> 7);
  if (mask[row]) return;  // masked rows fully written by gemm2
  out4[(size_t)row * 128 + (threadIdx.x & 127)] = float4{0.f, 0.f, 0.f, 0.f};
}

// 1024-thread per-expert compaction (16 scan iterations).
__global__ void compact_mask(const int* __restrict__ mask, int* __restrict__ idx,
                             int* __restrict__ counts) {
  int e = blockIdx.x;
  __shared__ int wsum[16];
  __shared__ int base;
  if (threadIdx.x == 0) base = 0;
  const int* m = mask + (size_t)e * TOK;
  int lane = threadIdx.x & 63, w = threadIdx.x >> 6;
  for (int c0 = 0; c0 < TOK; c0 += 1024) {
    __syncthreads();
    int i = c0 + threadIdx.x;
    int mi = (m[i] != 0);
    unsigned long long b = __ballot(mi);
    if (lane == 0) wsum[w] = __popcll(b);
    __syncthreads();
    int off = base;
    for (int ww = 0; ww < w; ww++) off += wsum[ww];
    off += __popcll(b & ((1ull << lane) - 1ull));
    if (mi) idx[(size_t)e * TOK + off] = i;
    __syncthreads();
    if (threadIdx.x == 0) {
      int s = 0;
      #pragma unroll
      for (int k = 0; k < 16; k++) s += wsum[k];
      base += s;
    }
  }
  __syncthreads();
  if (threadIdx.x == 0) counts[e] = base;
}

// Gather compacted token rows of x into xc[e][HP][512] bf16 (clamped pad rows).
// Makes gemm1's B-side a 4.7 MB/expert L2-resident linear stream.
__global__ void gather_xc(const float* __restrict__ x, const int* __restrict__ idx,
                          const int* __restrict__ counts, u16* __restrict__ xc) {
  int e = blockIdx.y;
  int r = blockIdx.x * 2 + (threadIdx.x >> 7);
  int cnt = counts[e];
  int rr = r < cnt ? r : cnt - 1;
  int tok = idx[(size_t)e * TOK + rr];
  int c4 = (threadIdx.x & 127) << 2;
  float4 v = *(const float4*)(x + (size_t)tok * ND + c4);
  union { u16 s[4]; u64 ll; } o;
  o.s[0] = f2bf(v.x); o.s[1] = f2bf(v.y); o.s[2] = f2bf(v.z); o.s[3] = f2bf(v.w);
  *(u64*)(xc + ((size_t)e * HP + r) * ND + c4) = o.ll;
}

// GEMM1: h[t][f] = gelu(xc @ W1 + b1). A=W1t rows f, B=xc rows t (both linear,
// pitch 1024B). 128x128 tile, BK=32, 16 steps, 32 KB LDS dbuf, 4 waves (64x64).
__launch_bounds__(256, 4)
__global__ void gemm1(const u16* __restrict__ xc, const u16* __restrict__ W1t,
                      const float* __restrict__ b1f,
                      const int* __restrict__ counts, u16* __restrict__ h) {
  const int BPE = (NF / 128) * MT;   // 576
  int bid = blockIdx.x;
  int e = bid / BPE, r = bid % BPE;
  int f0 = (r / MT) * 128, t0 = (r % MT) * 128;
  int cnt = counts[e];
  if (t0 >= cnt) return;

  __shared__ __align__(16) u16 As[2][4096];  // [buf][128 f][32 d]
  __shared__ __align__(16) u16 Bs[2][4096];  // [buf][128 t][32 d]

  int tid = threadIdx.x, lane = tid & 63, w = tid >> 6;
  int wm = w & 1, wn = w >> 1;
  int l15 = lane & 15, l4 = lane >> 4;

  int srow = lane >> 2, scolb = (lane & 3) << 4;
  int ar0 = w * 16 + srow, ar1 = 64 + w * 16 + srow;
  const char* xb = (const char*)xc;
  const char* w1 = (const char*)W1t;
  size_t asrc0 = ((size_t)e * NF + f0 + ar0) * 1024 + (scolb ^ swzr(ar0));
  size_t asrc1 = ((size_t)e * NF + f0 + ar1) * 1024 + (scolb ^ swzr(ar1));
  size_t bsrc0 = ((size_t)e * HP + t0 + ar0) * 1024 + (scolb ^ swzr(ar0));
  size_t bsrc1 = ((size_t)e * HP + t0 + ar1) * 1024 + (scolb ^ swzr(ar1));

  int aoff[4], boff[4];
  #pragma unroll
  for (int i = 0; i < 4; i++) {
    int rowa = wm * 64 + i * 16 + l15;
    aoff[i] = rowa * 64 + ((l4 * 16) ^ swzr(rowa));
    int rowb = wn * 64 + i * 16 + l15;
    boff[i] = rowb * 64 + ((l4 * 16) ^ swzr(rowb));
  }

  auto STAGE = [&](int kb, int c) {
    char* ad = (char*)As + c * 8192 + w * 1024 + lane * 16;
    char* bd = (char*)Bs + c * 8192 + w * 1024 + lane * 16;
    gl_lds16(w1 + asrc0 + kb * 64, ad);
    gl_lds16(w1 + asrc1 + kb * 64, ad + 4096);
    gl_lds16(xb + bsrc0 + kb * 64, bd);
    gl_lds16(xb + bsrc1 + kb * 64, bd + 4096);
  };

  f32x4 acc[4][4];
  #pragma unroll
  for (int i = 0; i < 4; i++)
    #pragma unroll
    for (int j = 0; j < 4; j++) acc[i][j] = (f32x4)(0.0f);

  STAGE(0, 0);
  __syncthreads();
  #pragma unroll
  for (int kb = 0; kb < 16; ++kb) {
    int cur = kb & 1;
    if (kb < 15) STAGE(kb + 1, cur ^ 1);
    const char* ab = (const char*)As + cur * 8192;
    const char* bb = (const char*)Bs + cur * 8192;
    bf16x8 a[4], b[4];
    #pragma unroll
    for (int i = 0; i < 4; i++) a[i] = *(const bf16x8*)(ab + aoff[i]);
    #pragma unroll
    for (int j = 0; j < 4; j++) b[j] = *(const bf16x8*)(bb + boff[j]);
    #pragma unroll
    for (int i = 0; i < 4; i++)
      #pragma unroll
      for (int j = 0; j < 4; j++)
        acc[i][j] = __builtin_amdgcn_mfma_f32_16x16x32_bf16(a[i], b[j], acc[i][j], 0, 0, 0);
    __syncthreads();
  }

  // epilogue: gelu(acc + b1) -> h[t][f], packed u64 (4 consecutive f)
  #pragma unroll
  for (int i = 0; i < 4; i++) {
    int fb = f0 + wm * 64 + i * 16 + l4 * 4;
    f32x4 bv = *(const f32x4*)(b1f + (size_t)e * NF + fb);
    #pragma unroll
    for (int j = 0; j < 4; j++) {
      int t = t0 + wn * 64 + j * 16 + l15;
      union { u16 s[4]; u64 ll; } pk;
      #pragma unroll
      for (int jj = 0; jj < 4; jj++)
        pk.s[jj] = f2bf(gelu_fast(acc[i][j][jj] + bv[jj]));
      *(u64*)(h + ((size_t)e * HP + t) * NF + fb) = pk.ll;
    }
  }
}

// GEMM2: Y = h @ W2 + b2, scatter rows via idx. A=W2t rows d, B=h rows t
// (pitch 4096B). K=2048, 64 steps, same 2-buf structure.
__launch_bounds__(256, 4)
__global__ void gemm2(const u16* __restrict__ h, const u16* __restrict__ W2t,
                      const float* __restrict__ b2f, const int* __restrict__ idx,
                      const int* __restrict__ counts, float* __restrict__ out) {
  const int BPE = (ND / 128) * MT;   // 144
  int bid = blockIdx.x;
  int e = bid / BPE, r = bid % BPE;
  int d0 = (r / MT) * 128, t0 = (r % MT) * 128;
  int cnt = counts[e];
  if (t0 >= cnt) return;

  __shared__ __align__(16) u16 As[2][4096];  // [buf][128 d][32 f]
  __shared__ __align__(16) u16 Bs[2][4096];  // [buf][128 t][32 f]

  int tid = threadIdx.x, lane = tid & 63, w = tid >> 6;
  int wm = w & 1, wn = w >> 1;
  int l15 = lane & 15, l4 = lane >> 4;
  const int* idxe = idx + (size_t)e * TOK;

  int srow = lane >> 2, scolb = (lane & 3) << 4;
  int ar0 = w * 16 + srow, ar1 = 64 + w * 16 + srow;
  const char* hb = (const char*)h;
  const char* w2 = (const char*)W2t;
  size_t asrc0 = ((size_t)e * ND + d0 + ar0) * 4096 + (scolb ^ swzr(ar0));
  size_t asrc1 = ((size_t)e * ND + d0 + ar1) * 4096 + (scolb ^ swzr(ar1));
  size_t bsrc0 = ((size_t)e * HP + t0 + ar0) * 4096 + (scolb ^ swzr(ar0));
  size_t bsrc1 = ((size_t)e * HP + t0 + ar1) * 4096 + (scolb ^ swzr(ar1));

  int aoff[4], boff[4];
  #pragma unroll
  for (int i = 0; i < 4; i++) {
    int rowa = wm * 64 + i * 16 + l15;
    aoff[i] = rowa * 64 + ((l4 * 16) ^ swzr(rowa));
    int rowb = wn * 64 + i * 16 + l15;
    boff[i] = rowb * 64 + ((l4 * 16) ^ swzr(rowb));
  }

  auto STAGE = [&](int kb, int c) {
    char* ad = (char*)As + c * 8192 + w * 1024 + lane * 16;
    char* bd = (char*)Bs + c * 8192 + w * 1024 + lane * 16;
    gl_lds16(w2 + asrc0 + kb * 64, ad);
    gl_lds16(w2 + asrc1 + kb * 64, ad + 4096);
    gl_lds16(hb + bsrc0 + kb * 64, bd);
    gl_lds16(hb + bsrc1 + kb * 64, bd + 4096);
  };

  f32x4 acc[4][4];
  #pragma unroll
  for (int i = 0; i < 4; i++)
    #pragma unroll
    for (int j = 0; j < 4; j++) acc[i][j] = (f32x4)(0.0f);

  STAGE(0, 0);
  __syncthreads();
  #pragma unroll 2
  for (int kb = 0; kb < 64; ++kb) {
    int cur = kb & 1;
    if (kb < 63) STAGE(kb + 1, cur ^ 1);
    const char* ab = (const char*)As + cur * 8192;
    const char* bb = (const char*)Bs + cur * 8192;
    bf16x8 a[4], b[4];
    #pragma unroll
    for (int i = 0; i < 4; i++) a[i] = *(const bf16x8*)(ab + aoff[i]);
    #pragma unroll
    for (int j = 0; j < 4; j++) b[j] = *(const bf16x8*)(bb + boff[j]);
    #pragma unroll
    for (int i = 0; i < 4; i++)
      #pragma unroll
      for (int j = 0; j < 4; j++)
        acc[i][j] = __builtin_amdgcn_mfma_f32_16x16x32_bf16(a[i], b[j], acc[i][j], 0, 0, 0);
    __syncthreads();
  }

  // epilogue: +b2, f32x4 scatter per (i,j), 4 consecutive d per thread
  #pragma unroll
  for (int i = 0; i < 4; i++) {
    int db = d0 + wm * 64 + i * 16 + l4 * 4;
    f32x4 b2v = *(const f32x4*)(b2f + (size_t)e * ND + db);
    #pragma unroll
    for (int j = 0; j < 4; j++) {
      int t = t0 + wn * 64 + j * 16 + l15;
      if (t < cnt) {
        int tok = idxe[t];
        f32x4 v;
        #pragma unroll
        for (int jj = 0; jj < 4; jj++) v[jj] = acc[i][j][jj] + b2v[jj];
        *(f32x4*)(out + ((size_t)e * TOK + tok) * ND + db) = v;
      }
    }
  }
}

extern "C" void kernel_launch(void* const* d_in, const int* in_sizes, int n_in,
                              void* d_out, int out_size, void* d_ws, size_t ws_size,
                              hipStream_t stream) {
  const float* x  = (const float*)d_in[0];
  const float* W1 = (const float*)d_in[1];
  const float* b1 = (const float*)d_in[2];
  const float* W2 = (const float*)d_in[3];
  const float* b2 = (const float*)d_in[4];
  const int* mask = (const int*)d_in[5];

  char* ws = (char*)d_ws;
  int* counts = (int*)ws;                                   // 1 KiB
  int* idx    = (int*)(ws + 1024);                          // 512 KiB
  u16* W1t    = (u16*)(ws + 1024 + (size_t)NE * TOK * 4);   // 16 MiB  [E][f][d]
  u16* W2t    = W1t + (size_t)NE * NF * ND;                 // 16 MiB  [E][d][f]
  u16* xc     = W2t + (size_t)NE * ND * NF;                 // 37.75 MiB [E][HP][ND]
  u16* h      = xc + (size_t)NE * HP * ND;                  // 151 MiB [E][HP][NF]

  zero_unmasked<<<dim3(NE * TOK / 2), dim3(256), 0, stream>>>(mask, (float4*)d_out);
  transpose_bf16<<<dim3(NF / 32, ND / 32, NE), dim3(256), 0, stream>>>(W1, W1t, ND, NF);
  transpose_bf16<<<dim3(ND / 32, NF / 32, NE), dim3(256), 0, stream>>>(W2, W2t, NF, ND);
  compact_mask<<<dim3(NE), dim3(1024), 0, stream>>>(mask, idx, counts);
  gather_xc<<<dim3(HP / 2, NE), dim3(256), 0, stream>>>(x, idx, counts, xc);

  gemm1<<<dim3(NE * (NF / 128) * MT), dim3(256), 0, stream>>>(xc, W1t, b1, counts, h);
  gemm2<<<dim3(NE * (ND / 128) * MT), dim3(256), 0, stream>>>(h, W2t, b2, idx, counts,
                                                              (float*)d_out);
}

// Round 16
// 360.036 us; speedup vs baseline: 1.0716x; 1.0413x over previous
//
#include <hip/hip_runtime.h>
#include <hip/hip_bf16.h>

#define NE 8
#define TOK 16384
#define ND 512
#define NF 2048
#define HP 4608   // padded compact rows per expert (cnt ~4096, +9 sigma)
#define MT 36     // HP/128 t-tiles

typedef __attribute__((ext_vector_type(8))) short bf16x8;
typedef __attribute__((ext_vector_type(4))) float f32x4;
typedef unsigned short u16;
typedef unsigned long long u64;

__device__ __forceinline__ u16 f2bf(float f) {
  union { float f; unsigned u; } c; c.f = f;
  unsigned u = c.u;
  return (u16)((u + 0x7FFFu + ((u >> 16) & 1u)) >> 16);
}

// gelu(x) = x * (1 - 1/(exp2(K1*x + K2*x^3) + 1)),  K1 = sqrt(2/pi)*2*log2e
__device__ __forceinline__ float gelu_fast(float x) {
  float x2 = x * x;
  float zp = x * __builtin_fmaf(0.10294325f, x2, 2.3022084f);
  float u = __builtin_amdgcn_exp2f(zp);
  float r = __builtin_amdgcn_rcpf(u + 1.0f);   // u=inf -> r=0 -> y=x
  return x * (1.0f - r);
}

__device__ __forceinline__ void gl_lds16(const void* g, void* l) {
  __builtin_amdgcn_global_load_lds(
      (const __attribute__((address_space(1))) unsigned int*)g,
      (__attribute__((address_space(3))) unsigned int*)l, 16, 0, 0);
}

__device__ __forceinline__ int swzr(int row) { return ((row >> 1) & 3) << 4; }

// Transpose one [R][C] f32 plane per expert -> [C][R] bf16. (verified r10-r14)
__global__ void transpose_bf16(const float* __restrict__ in, u16* __restrict__ out,
                               int R, int C) {
  __shared__ float tile[32][33];
  int e = blockIdx.z;
  const float* ip = in + (size_t)e * R * C;
  u16* op = out + (size_t)e * R * C;
  int c0 = blockIdx.x * 32, r0 = blockIdx.y * 32;
  int tx = threadIdx.x & 31, ty = threadIdx.x >> 5;
  for (int i = 0; i < 32; i += 8)
    tile[ty + i][tx] = ip[(size_t)(r0 + ty + i) * C + (c0 + tx)];
  __syncthreads();
  for (int i = 0; i < 32; i += 8)
    op[(size_t)(c0 + ty + i) * R + (r0 + tx)] = f2bf(tile[tx][ty + i]);
}

__global__ void zero_unmasked(const int* __restrict__ mask, float4* __restrict__ out4) {
  int row = blockIdx.x * 2 + (threadIdx.x >> 7);
  if (mask[row]) return;  // masked rows fully written by gemm2
  out4[(size_t)row * 128 + (threadIdx.x & 127)] = float4{0.f, 0.f, 0.f, 0.f};
}

// 1024-thread per-expert compaction (16 scan iterations).
__global__ void compact_mask(const int* __restrict__ mask, int* __restrict__ idx,
                             int* __restrict__ counts) {
  int e = blockIdx.x;
  __shared__ int wsum[16];
  __shared__ int base;
  if (threadIdx.x == 0) base = 0;
  const int* m = mask + (size_t)e * TOK;
  int lane = threadIdx.x & 63, w = threadIdx.x >> 6;
  for (int c0 = 0; c0 < TOK; c0 += 1024) {
    __syncthreads();
    int i = c0 + threadIdx.x;
    int mi = (m[i] != 0);
    unsigned long long b = __ballot(mi);
    if (lane == 0) wsum[w] = __popcll(b);
    __syncthreads();
    int off = base;
    for (int ww = 0; ww < w; ww++) off += wsum[ww];
    off += __popcll(b & ((1ull << lane) - 1ull));
    if (mi) idx[(size_t)e * TOK + off] = i;
    __syncthreads();
    if (threadIdx.x == 0) {
      int s = 0;
      #pragma unroll
      for (int k = 0; k < 16; k++) s += wsum[k];
      base += s;
    }
  }
  __syncthreads();
  if (threadIdx.x == 0) counts[e] = base;
}

// Gather compacted token rows of x into xc[e][HP][512] bf16 (clamped pad rows).
__global__ void gather_xc(const float* __restrict__ x, const int* __restrict__ idx,
                          const int* __restrict__ counts, u16* __restrict__ xc) {
  int e = blockIdx.y;
  int r = blockIdx.x * 2 + (threadIdx.x >> 7);
  int cnt = counts[e];
  int rr = r < cnt ? r : cnt - 1;
  int tok = idx[(size_t)e * TOK + rr];
  int c4 = (threadIdx.x & 127) << 2;
  float4 v = *(const float4*)(x + (size_t)tok * ND + c4);
  union { u16 s[4]; u64 ll; } o;
  o.s[0] = f2bf(v.x); o.s[1] = f2bf(v.y); o.s[2] = f2bf(v.z); o.s[3] = f2bf(v.w);
  *(u64*)(xc + ((size_t)e * HP + r) * ND + c4) = o.ll;
}

// GEMM1: h[t][f] = gelu(xc @ W1 + b1). Expert<->XCD affine: e = bid&7 (round-robin
// block->XCD dispatch) so W1t (2.1 MB/expert) is L2-resident; l = bid>>3 ordered
// t-major (16 f-tiles share one xc t-panel -> L2 temporal reuse).
__launch_bounds__(256, 4)
__global__ void gemm1(const u16* __restrict__ xc, const u16* __restrict__ W1t,
                      const float* __restrict__ b1f,
                      const int* __restrict__ counts, u16* __restrict__ h) {
  int e = blockIdx.x & 7;
  int l = blockIdx.x >> 3;            // 0..575
  int t0 = (l >> 4) * 128;            // l / 16
  int f0 = (l & 15) * 128;            // l % 16
  int cnt = counts[e];
  if (t0 >= cnt) return;

  __shared__ __align__(16) u16 As[2][4096];  // [buf][128 f][32 d]
  __shared__ __align__(16) u16 Bs[2][4096];  // [buf][128 t][32 d]

  int tid = threadIdx.x, lane = tid & 63, w = tid >> 6;
  int wm = w & 1, wn = w >> 1;
  int l15 = lane & 15, l4 = lane >> 4;

  int srow = lane >> 2, scolb = (lane & 3) << 4;
  int ar0 = w * 16 + srow, ar1 = 64 + w * 16 + srow;
  const char* xb = (const char*)xc;
  const char* w1 = (const char*)W1t;
  size_t asrc0 = ((size_t)e * NF + f0 + ar0) * 1024 + (scolb ^ swzr(ar0));
  size_t asrc1 = ((size_t)e * NF + f0 + ar1) * 1024 + (scolb ^ swzr(ar1));
  size_t bsrc0 = ((size_t)e * HP + t0 + ar0) * 1024 + (scolb ^ swzr(ar0));
  size_t bsrc1 = ((size_t)e * HP + t0 + ar1) * 1024 + (scolb ^ swzr(ar1));

  int aoff[4], boff[4];
  #pragma unroll
  for (int i = 0; i < 4; i++) {
    int rowa = wm * 64 + i * 16 + l15;
    aoff[i] = rowa * 64 + ((l4 * 16) ^ swzr(rowa));
    int rowb = wn * 64 + i * 16 + l15;
    boff[i] = rowb * 64 + ((l4 * 16) ^ swzr(rowb));
  }

  auto STAGE = [&](int kb, int c) {
    char* ad = (char*)As + c * 8192 + w * 1024 + lane * 16;
    char* bd = (char*)Bs + c * 8192 + w * 1024 + lane * 16;
    gl_lds16(w1 + asrc0 + kb * 64, ad);
    gl_lds16(w1 + asrc1 + kb * 64, ad + 4096);
    gl_lds16(xb + bsrc0 + kb * 64, bd);
    gl_lds16(xb + bsrc1 + kb * 64, bd + 4096);
  };

  f32x4 acc[4][4];
  #pragma unroll
  for (int i = 0; i < 4; i++)
    #pragma unroll
    for (int j = 0; j < 4; j++) acc[i][j] = (f32x4)(0.0f);

  STAGE(0, 0);
  __syncthreads();
  #pragma unroll
  for (int kb = 0; kb < 16; ++kb) {
    int cur = kb & 1;
    if (kb < 15) STAGE(kb + 1, cur ^ 1);
    const char* ab = (const char*)As + cur * 8192;
    const char* bb = (const char*)Bs + cur * 8192;
    bf16x8 a[4], b[4];
    #pragma unroll
    for (int i = 0; i < 4; i++) a[i] = *(const bf16x8*)(ab + aoff[i]);
    #pragma unroll
    for (int j = 0; j < 4; j++) b[j] = *(const bf16x8*)(bb + boff[j]);
    #pragma unroll
    for (int i = 0; i < 4; i++)
      #pragma unroll
      for (int j = 0; j < 4; j++)
        acc[i][j] = __builtin_amdgcn_mfma_f32_16x16x32_bf16(a[i], b[j], acc[i][j], 0, 0, 0);
    __syncthreads();
  }

  // epilogue: gelu(acc + b1) -> h[t][f], packed u64 (4 consecutive f)
  #pragma unroll
  for (int i = 0; i < 4; i++) {
    int fb = f0 + wm * 64 + i * 16 + l4 * 4;
    f32x4 bv = *(const f32x4*)(b1f + (size_t)e * NF + fb);
    #pragma unroll
    for (int j = 0; j < 4; j++) {
      int t = t0 + wn * 64 + j * 16 + l15;
      union { u16 s[4]; u64 ll; } pk;
      #pragma unroll
      for (int jj = 0; jj < 4; jj++)
        pk.s[jj] = f2bf(gelu_fast(acc[i][j][jj] + bv[jj]));
      *(u64*)(h + ((size_t)e * HP + t) * NF + fb) = pk.ll;
    }
  }
}

// GEMM2: Y = h @ W2 + b2, scatter rows via idx. Expert<->XCD affine; l ordered
// t-major (the 4 d-tiles sharing one h t-panel are adjacent -> h read ~once).
__launch_bounds__(256, 4)
__global__ void gemm2(const u16* __restrict__ h, const u16* __restrict__ W2t,
                      const float* __restrict__ b2f, const int* __restrict__ idx,
                      const int* __restrict__ counts, float* __restrict__ out) {
  int e = blockIdx.x & 7;
  int l = blockIdx.x >> 3;            // 0..143
  int t0 = (l >> 2) * 128;            // l / 4
  int d0 = (l & 3) * 128;             // l % 4
  int cnt = counts[e];
  if (t0 >= cnt) return;

  __shared__ __align__(16) u16 As[2][4096];  // [buf][128 d][32 f]
  __shared__ __align__(16) u16 Bs[2][4096];  // [buf][128 t][32 f]

  int tid = threadIdx.x, lane = tid & 63, w = tid >> 6;
  int wm = w & 1, wn = w >> 1;
  int l15 = lane & 15, l4 = lane >> 4;
  const int* idxe = idx + (size_t)e * TOK;

  int srow = lane >> 2, scolb = (lane & 3) << 4;
  int ar0 = w * 16 + srow, ar1 = 64 + w * 16 + srow;
  const char* hb = (const char*)h;
  const char* w2 = (const char*)W2t;
  size_t asrc0 = ((size_t)e * ND + d0 + ar0) * 4096 + (scolb ^ swzr(ar0));
  size_t asrc1 = ((size_t)e * ND + d0 + ar1) * 4096 + (scolb ^ swzr(ar1));
  size_t bsrc0 = ((size_t)e * HP + t0 + ar0) * 4096 + (scolb ^ swzr(ar0));
  size_t bsrc1 = ((size_t)e * HP + t0 + ar1) * 4096 + (scolb ^ swzr(ar1));

  int aoff[4], boff[4];
  #pragma unroll
  for (int i = 0; i < 4; i++) {
    int rowa = wm * 64 + i * 16 + l15;
    aoff[i] = rowa * 64 + ((l4 * 16) ^ swzr(rowa));
    int rowb = wn * 64 + i * 16 + l15;
    boff[i] = rowb * 64 + ((l4 * 16) ^ swzr(rowb));
  }

  auto STAGE = [&](int kb, int c) {
    char* ad = (char*)As + c * 8192 + w * 1024 + lane * 16;
    char* bd = (char*)Bs + c * 8192 + w * 1024 + lane * 16;
    gl_lds16(w2 + asrc0 + kb * 64, ad);
    gl_lds16(w2 + asrc1 + kb * 64, ad + 4096);
    gl_lds16(hb + bsrc0 + kb * 64, bd);
    gl_lds16(hb + bsrc1 + kb * 64, bd + 4096);
  };

  f32x4 acc[4][4];
  #pragma unroll
  for (int i = 0; i < 4; i++)
    #pragma unroll
    for (int j = 0; j < 4; j++) acc[i][j] = (f32x4)(0.0f);

  STAGE(0, 0);
  __syncthreads();
  #pragma unroll 2
  for (int kb = 0; kb < 64; ++kb) {
    int cur = kb & 1;
    if (kb < 63) STAGE(kb + 1, cur ^ 1);
    const char* ab = (const char*)As + cur * 8192;
    const char* bb = (const char*)Bs + cur * 8192;
    bf16x8 a[4], b[4];
    #pragma unroll
    for (int i = 0; i < 4; i++) a[i] = *(const bf16x8*)(ab + aoff[i]);
    #pragma unroll
    for (int j = 0; j < 4; j++) b[j] = *(const bf16x8*)(bb + boff[j]);
    #pragma unroll
    for (int i = 0; i < 4; i++)
      #pragma unroll
      for (int j = 0; j < 4; j++)
        acc[i][j] = __builtin_amdgcn_mfma_f32_16x16x32_bf16(a[i], b[j], acc[i][j], 0, 0, 0);
    __syncthreads();
  }

  // epilogue: +b2, f32x4 scatter per (i,j), 4 consecutive d per thread
  #pragma unroll
  for (int i = 0; i < 4; i++) {
    int db = d0 + wm * 64 + i * 16 + l4 * 4;
    f32x4 b2v = *(const f32x4*)(b2f + (size_t)e * ND + db);
    #pragma unroll
    for (int j = 0; j < 4; j++) {
      int t = t0 + wn * 64 + j * 16 + l15;
      if (t < cnt) {
        int tok = idxe[t];
        f32x4 v;
        #pragma unroll
        for (int jj = 0; jj < 4; jj++) v[jj] = acc[i][j][jj] + b2v[jj];
        *(f32x4*)(out + ((size_t)e * TOK + tok) * ND + db) = v;
      }
    }
  }
}

extern "C" void kernel_launch(void* const* d_in, const int* in_sizes, int n_in,
                              void* d_out, int out_size, void* d_ws, size_t ws_size,
                              hipStream_t stream) {
  const float* x  = (const float*)d_in[0];
  const float* W1 = (const float*)d_in[1];
  const float* b1 = (const float*)d_in[2];
  const float* W2 = (const float*)d_in[3];
  const float* b2 = (const float*)d_in[4];
  const int* mask = (const int*)d_in[5];

  char* ws = (char*)d_ws;
  int* counts = (int*)ws;                                   // 1 KiB
  int* idx    = (int*)(ws + 1024);                          // 512 KiB
  u16* W1t    = (u16*)(ws + 1024 + (size_t)NE * TOK * 4);   // 16 MiB  [E][f][d]
  u16* W2t    = W1t + (size_t)NE * NF * ND;                 // 16 MiB  [E][d][f]
  u16* xc     = W2t + (size_t)NE * ND * NF;                 // 37.75 MiB [E][HP][ND]
  u16* h      = xc + (size_t)NE * HP * ND;                  // 151 MiB [E][HP][NF]

  zero_unmasked<<<dim3(NE * TOK / 2), dim3(256), 0, stream>>>(mask, (float4*)d_out);
  transpose_bf16<<<dim3(NF / 32, ND / 32, NE), dim3(256), 0, stream>>>(W1, W1t, ND, NF);
  transpose_bf16<<<dim3(ND / 32, NF / 32, NE), dim3(256), 0, stream>>>(W2, W2t, NF, ND);
  compact_mask<<<dim3(NE), dim3(1024), 0, stream>>>(mask, idx, counts);
  gather_xc<<<dim3(HP / 2, NE), dim3(256), 0, stream>>>(x, idx, counts, xc);

  gemm1<<<dim3(NE * (NF / 128) * MT), dim3(256), 0, stream>>>(xc, W1t, b1, counts, h);
  gemm2<<<dim3(NE * (ND / 128) * MT), dim3(256), 0, stream>>>(h, W2t, b2, idx, counts,
                                                              (float*)d_out);
}